// Round 7
// baseline (96.398 us; speedup 1.0000x reference)
//
#include <hip/hip_runtime.h>
#include <hip/hip_bf16.h>
#include <math.h>

#define SS 2048
#define HH 16
#define DD 128
#define HD (HH*DD)
#define QB 128          // q-rows per block (4 waves x 32)
#define KVB 64          // kv-tile

typedef __attribute__((ext_vector_type(8))) short bf16x8;
typedef __attribute__((ext_vector_type(16))) float f32x16;

__device__ __forceinline__ ushort f2bf(float f) {
  __hip_bfloat16 h = __float2bfloat16(f);
  return __builtin_bit_cast(ushort, h);
}
__device__ __forceinline__ uint pk2(float a, float b) {   // low=a, high=b
  return ((uint)f2bf(b) << 16) | (uint)f2bf(a);
}
__device__ __forceinline__ float bf2f(ushort u) {
  uint x = ((uint)u) << 16;
  return __builtin_bit_cast(float, x);
}

// ---------------------------------------------------------------------------
// Partial flash attention. Job = (h, pp, jj): pair (qt=pp, qt=15-pp), tiles
// split at {0,8,17,25,34} over the concatenated tile list. 32x32 MFMA,
// swapped QK^T (S^T), in-register P, O^T accumulator, swizzled LDS.
// ---------------------------------------------------------------------------
__global__ __launch_bounds__(256, 2)
void attn_fwd(const float* __restrict__ Q, const float* __restrict__ K,
              const float* __restrict__ V,
              ushort* __restrict__ PO, float* __restrict__ PM,
              float* __restrict__ PL) {
  __shared__ alignas(16) ushort Klds[KVB * DD];    // [64][128] bf16, swizzled
  __shared__ alignas(16) ushort VTlds[DD * KVB];   // [128][64] bf16, swizzled

  const int tid  = threadIdx.x;
  const int lane = tid & 63;
  const int wid  = tid >> 6;       // 0..3
  const int q32  = lane & 31;
  const int hi   = lane >> 5;
  const int swz  = (q32 & 7) << 4;

  const int bx   = blockIdx.x;
  const int h    = bx & 15;
  const int rest = bx >> 4;        // 0..31
  const int pp   = rest >> 2;      // 0..7
  const int jj   = rest & 3;       // 0..3
  const int LA   = 2 * pp + 2;     // tiles of small q-tile
  const int BND[5] = {0, 8, 17, 25, 34};
  const int tl = BND[jj], th = BND[jj + 1];

  const float SCALE = 1.44269504088896f / sqrtf((float)DD);
  const float* Kb = K + (size_t)h * DD;
  const float* Vb = V + (size_t)h * DD;

  float kf[4][8];
  float vf[4][8];

  for (int phase = 0; phase < 2; ++phase) {
    int qt, lo, hiT;
    if (phase == 0) { qt = pp;      lo = tl;                    hiT = min(th, LA); }
    else            { qt = 15 - pp; lo = max(tl, LA) - LA;      hiT = th - LA; }
    if (lo >= hiT) continue;

    const int qb = qt * QB;
    const int qw = qb + 32 * wid;      // wave's first q row
    const int qg = qw + q32;           // this lane's q row

    // ---- Q fragments (B operand): qf[ks] = Q[qg][16ks+8hi+0..7] * SCALE ----
    bf16x8 qf[8];
    {
      const float* qr = Q + ((size_t)qg * HH + h) * DD;
      #pragma unroll
      for (int ks = 0; ks < 8; ++ks) {
        float4 x = *(const float4*)&qr[16 * ks + 8 * hi];
        float4 y = *(const float4*)&qr[16 * ks + 8 * hi + 4];
        uint4 u;
        u.x = pk2(x.x * SCALE, x.y * SCALE);
        u.y = pk2(x.z * SCALE, x.w * SCALE);
        u.z = pk2(y.x * SCALE, y.y * SCALE);
        u.w = pk2(y.z * SCALE, y.w * SCALE);
        qf[ks] = __builtin_bit_cast(bf16x8, u);
      }
    }

    f32x16 acc[4];
    #pragma unroll
    for (int dt = 0; dt < 4; ++dt)
      #pragma unroll
      for (int e = 0; e < 16; ++e) acc[dt][e] = 0.f;
    float m = -1e30f, l = 0.f;

    // ---- prefetch tile lo ----
    {
      const int t0 = lo * KVB;
      #pragma unroll
      for (int it = 0; it < 4; ++it) {
        int e = tid + it * 256;
        int row = e >> 4, col = (e & 15) * 8;
        const float* src = &Kb[(size_t)(t0 + row) * HD + col];
        float4 a = *(const float4*)src;
        float4 b = *(const float4*)(src + 4);
        kf[it][0]=a.x; kf[it][1]=a.y; kf[it][2]=a.z; kf[it][3]=a.w;
        kf[it][4]=b.x; kf[it][5]=b.y; kf[it][6]=b.z; kf[it][7]=b.w;
        int d = e >> 3, tc = (e & 7) * 8;
        #pragma unroll
        for (int j2 = 0; j2 < 8; ++j2)
          vf[it][j2] = Vb[(size_t)(t0 + tc + j2) * HD + d];
      }
    }

    for (int itile = lo; itile < hiT; ++itile) {
      __syncthreads();   // previous tile's LDS fully consumed
      // ---- stage (convert + swizzled b128 writes) ----
      #pragma unroll
      for (int it = 0; it < 4; ++it) {
        int e = tid + it * 256;
        int row = e >> 4;
        uint4 u;
        u.x = pk2(kf[it][0], kf[it][1]); u.y = pk2(kf[it][2], kf[it][3]);
        u.z = pk2(kf[it][4], kf[it][5]); u.w = pk2(kf[it][6], kf[it][7]);
        *(uint4*)((char*)Klds + ((e * 16) ^ ((row & 7) << 4))) = u;
        int d = e >> 3;
        uint4 v;
        v.x = pk2(vf[it][0], vf[it][1]); v.y = pk2(vf[it][2], vf[it][3]);
        v.z = pk2(vf[it][4], vf[it][5]); v.w = pk2(vf[it][6], vf[it][7]);
        *(uint4*)((char*)VTlds + ((e * 16) ^ ((d & 7) << 4))) = v;
      }
      __syncthreads();   // tile ready

      // ---- prefetch next tile ----
      if (itile + 1 < hiT) {
        const int t0n = (itile + 1) * KVB;
        #pragma unroll
        for (int it = 0; it < 4; ++it) {
          int e = tid + it * 256;
          int row = e >> 4, col = (e & 15) * 8;
          const float* src = &Kb[(size_t)(t0n + row) * HD + col];
          float4 a = *(const float4*)src;
          float4 b = *(const float4*)(src + 4);
          kf[it][0]=a.x; kf[it][1]=a.y; kf[it][2]=a.z; kf[it][3]=a.w;
          kf[it][4]=b.x; kf[it][5]=b.y; kf[it][6]=b.z; kf[it][7]=b.w;
          int d = e >> 3, tc = (e & 7) * 8;
          #pragma unroll
          for (int j2 = 0; j2 < 8; ++j2)
            vf[it][j2] = Vb[(size_t)(t0n + tc + j2) * HD + d];
        }
      }

      const int t0 = itile * KVB;

      // ---- QK^T swapped: s0 = S^T[t0..t0+31][q], s1 = S^T[t0+32..][q] ----
      f32x16 s0, s1;
      #pragma unroll
      for (int e = 0; e < 16; ++e) { s0[e] = 0.f; s1[e] = 0.f; }
      __builtin_amdgcn_s_setprio(1);
      #pragma unroll
      for (int ks = 0; ks < 8; ++ks) {
        bf16x8 a0 = *(const bf16x8*)((const char*)Klds +
                      ((q32 * 256 + 32 * ks + 16 * hi) ^ swz));
        s0 = __builtin_amdgcn_mfma_f32_32x32x16_bf16(a0, qf[ks], s0, 0, 0, 0);
      }
      #pragma unroll
      for (int ks = 0; ks < 8; ++ks) {
        bf16x8 a1 = *(const bf16x8*)((const char*)Klds +
                      (((q32 + 32) * 256 + 32 * ks + 16 * hi) ^ swz));
        s1 = __builtin_amdgcn_mfma_f32_32x32x16_bf16(a1, qf[ks], s1, 0, 0, 0);
      }
      __builtin_amdgcn_s_setprio(0);

      // ---- causal mask (lane holds t = t0 + 32*half + (e&3)+8*(e>>2)+4hi) ----
      if (t0 + KVB - 1 > qw) {
        #pragma unroll
        for (int e = 0; e < 16; ++e) {
          int tloc = (e & 3) + 8 * (e >> 2) + 4 * hi;
          if (t0 + tloc > qg)      s0[e] = -INFINITY;
          if (t0 + 32 + tloc > qg) s1[e] = -INFINITY;
        }
      }

      // ---- online softmax, fully in-register ----
      float mr = -1e30f;
      #pragma unroll
      for (int e = 0; e < 16; ++e) mr = fmaxf(mr, fmaxf(s0[e], s1[e]));
      mr = fmaxf(mr, __shfl_xor(mr, 32));
      float mn = fmaxf(m, mr);
      float corr = exp2f(m - mn);
      m = mn;
      float ps = 0.f;
      #pragma unroll
      for (int e = 0; e < 16; ++e) {
        float p0 = exp2f(s0[e] - m); s0[e] = p0; ps += p0;
        float p1 = exp2f(s1[e] - m); s1[e] = p1; ps += p1;
      }
      ps += __shfl_xor(ps, 32);
      l = l * corr + ps;
      #pragma unroll
      for (int dt = 0; dt < 4; ++dt)
        #pragma unroll
        for (int e = 0; e < 16; ++e) acc[dt][e] *= corr;

      // ---- P -> bf16 B-fragments (cvt_pk pairs + lane<->lane+32 exchange) ----
      uint4 paf[4];
      #pragma unroll
      for (int tk = 0; tk < 4; ++tk) {
        float p0,p1,p2,p3,p4,p5,p6,p7;
        if (tk == 0) { p0=s0[0];p1=s0[1];p2=s0[2];p3=s0[3];p4=s0[4];p5=s0[5];p6=s0[6];p7=s0[7]; }
        else if (tk == 1) { p0=s0[8];p1=s0[9];p2=s0[10];p3=s0[11];p4=s0[12];p5=s0[13];p6=s0[14];p7=s0[15]; }
        else if (tk == 2) { p0=s1[0];p1=s1[1];p2=s1[2];p3=s1[3];p4=s1[4];p5=s1[5];p6=s1[6];p7=s1[7]; }
        else { p0=s1[8];p1=s1[9];p2=s1[10];p3=s1[11];p4=s1[12];p5=s1[13];p6=s1[14];p7=s1[15]; }
        uint A0 = pk2(p0, p1), A1 = pk2(p2, p3);
        uint B0 = pk2(p4, p5), B1 = pk2(p6, p7);
        uint x0 = hi ? A0 : B0, x1 = hi ? A1 : B1;
        uint r0 = (uint)__shfl_xor((int)x0, 32);
        uint r1 = (uint)__shfl_xor((int)x1, 32);
        paf[tk].x = hi ? r0 : A0;
        paf[tk].y = hi ? r1 : A1;
        paf[tk].z = hi ? B0 : r0;
        paf[tk].w = hi ? B1 : r1;
      }

      // ---- PV: acc[dt] = O^T[d-tile][q] += V^T x P^T ----
      __builtin_amdgcn_s_setprio(1);
      #pragma unroll
      for (int dt = 0; dt < 4; ++dt) {
        #pragma unroll
        for (int tk = 0; tk < 4; ++tk) {
          bf16x8 va = *(const bf16x8*)((const char*)VTlds +
                        (((dt * 32 + q32) * 128 + 32 * tk + 16 * hi) ^ swz));
          bf16x8 pb = __builtin_bit_cast(bf16x8, paf[tk]);
          acc[dt] = __builtin_amdgcn_mfma_f32_32x32x16_bf16(va, pb, acc[dt], 0, 0, 0);
        }
      }
      __builtin_amdgcn_s_setprio(0);
    }

    // ---- partial epilogue (unnormalized, bf16) ----
    const int slot = (((h * 8 + pp) * 4 + jj) * 2) + phase;
    ushort* po = PO + (size_t)slot * (QB * DD);
    const int row = 32 * wid + q32;
    #pragma unroll
    for (int dt = 0; dt < 4; ++dt) {
      #pragma unroll
      for (int rq = 0; rq < 4; ++rq) {
        int d = 32 * dt + 8 * rq + 4 * hi;
        uint2 w;
        w.x = pk2(acc[dt][4 * rq + 0], acc[dt][4 * rq + 1]);
        w.y = pk2(acc[dt][4 * rq + 2], acc[dt][4 * rq + 3]);
        *(uint2*)&po[row * DD + d] = w;
      }
    }
    if (hi == 0) {
      PM[(size_t)slot * QB + row] = m;
      PL[(size_t)slot * QB + row] = l;
    }
  }
}

// ---------------------------------------------------------------------------
// Merge 1-4 partials per (h, qt).
// ---------------------------------------------------------------------------
__global__ __launch_bounds__(256, 4)
void attn_merge(const ushort* __restrict__ PO, const float* __restrict__ PM,
                const float* __restrict__ PL, float* __restrict__ O) {
  const int bx  = blockIdx.x;      // 256 = 16 qt * 16 h
  const int h   = bx & 15;
  const int qt  = bx >> 4;
  const int tid = threadIdx.x;
  const int r   = tid >> 1;        // 0..127
  const int dh  = (tid & 1) * 64;

  const int BND[5] = {0, 8, 17, 25, 34};
  const int pp    = (qt < 8) ? qt : (15 - qt);
  const int phase = (qt < 8) ? 0 : 1;
  const int LA    = 2 * pp + 2;

  float mv[4], lv[4];
  float M = -1e30f;
  #pragma unroll
  for (int jj = 0; jj < 4; ++jj) {
    bool inc = (phase == 0) ? (BND[jj] < LA) : (BND[jj + 1] > LA);
    int slot = (((h * 8 + pp) * 4 + jj) * 2) + phase;
    mv[jj] = inc ? PM[(size_t)slot * QB + r] : -1e30f;
    lv[jj] = inc ? PL[(size_t)slot * QB + r] : 0.f;
    M = fmaxf(M, mv[jj]);
  }
  float L = 0.f;
  float o[64];
  #pragma unroll
  for (int k2 = 0; k2 < 64; ++k2) o[k2] = 0.f;
  #pragma unroll
  for (int jj = 0; jj < 4; ++jj) {
    bool inc = (phase == 0) ? (BND[jj] < LA) : (BND[jj + 1] > LA);
    if (!inc) continue;
    int slot = (((h * 8 + pp) * 4 + jj) * 2) + phase;
    float w = exp2f(mv[jj] - M);
    L += lv[jj] * w;
    const ushort* src = PO + (size_t)slot * (QB * DD) + r * DD + dh;
    #pragma unroll
    for (int k4 = 0; k4 < 16; ++k4) {
      ushort4 u = *(const ushort4*)&src[4 * k4];
      o[4*k4+0] += bf2f(u.x) * w;
      o[4*k4+1] += bf2f(u.y) * w;
      o[4*k4+2] += bf2f(u.z) * w;
      o[4*k4+3] += bf2f(u.w) * w;
    }
  }
  float inv = 1.0f / L;
  float* op = O + ((size_t)(qt * QB + r) * HH + h) * DD + dh;
  #pragma unroll
  for (int k4 = 0; k4 < 16; ++k4) {
    float4 x = make_float4(o[4*k4]*inv, o[4*k4+1]*inv, o[4*k4+2]*inv, o[4*k4+3]*inv);
    *(float4*)&op[4 * k4] = x;
  }
}

extern "C" void kernel_launch(void* const* d_in, const int* in_sizes, int n_in,
                              void* d_out, int out_size, void* d_ws, size_t ws_size,
                              hipStream_t stream) {
  const float* Q = (const float*)d_in[0];
  const float* K = (const float*)d_in[1];
  const float* V = (const float*)d_in[2];
  float* O = (float*)d_out;

  const size_t po_elems = (size_t)1024 * QB * DD;        // bf16: 32 MB
  ushort* PO = (ushort*)d_ws;
  float*  PM = (float*)(PO + po_elems);                  // 1024*128 f32
  float*  PL = PM + (size_t)1024 * QB;

  attn_fwd<<<dim3(512), 256, 0, stream>>>(Q, K, V, PO, PM, PL);
  attn_merge<<<dim3(256), 256, 0, stream>>>(PO, PM, PL, O);
}

// Round 8
// 69.798 us; speedup vs baseline: 1.3811x; 1.3811x over previous
//
#include <hip/hip_runtime.h>
#include <hip/hip_bf16.h>
#include <math.h>

#define SS 2048
#define HH 16
#define DD 128
#define HD (HH*DD)
#define QB 128          // q-rows per block (4 waves x 32)
#define KVB 64          // kv-tile

typedef __attribute__((ext_vector_type(8))) short bf16x8;
typedef __attribute__((ext_vector_type(16))) float f32x16;

__device__ __forceinline__ ushort f2bf(float f) {
  __hip_bfloat16 h = __float2bfloat16(f);
  return __builtin_bit_cast(ushort, h);
}
__device__ __forceinline__ uint pk2(float a, float b) {   // low=a, high=b
  return ((uint)f2bf(b) << 16) | (uint)f2bf(a);
}
__device__ __forceinline__ float bf2f(ushort u) {
  uint x = ((uint)u) << 16;
  return __builtin_bit_cast(float, x);
}

// ---------------------------------------------------------------------------
// Partial flash attention. Job = (h, pp, jj): pair (qt=pp, qt=15-pp), tiles
// split at {0,8,17,25,34}. 32x32 MFMA, swapped QK^T (S^T), in-register P,
// O^T accumulator, swizzled LDS. V staged via coalesced 4-row column gather.
// ---------------------------------------------------------------------------
__global__ __launch_bounds__(256, 2)
void attn_fwd(const float* __restrict__ Q, const float* __restrict__ K,
              const float* __restrict__ V,
              ushort* __restrict__ PO, float* __restrict__ PM,
              float* __restrict__ PL) {
  __shared__ alignas(16) ushort Klds[KVB * DD];    // [64 t][128 d] bf16, swizzled
  __shared__ alignas(16) ushort VTlds[DD * KVB];   // [128 d][64 t] bf16, swizzled

  const int tid  = threadIdx.x;
  const int lane = tid & 63;
  const int wid  = tid >> 6;       // 0..3
  const int q32  = lane & 31;
  const int hi   = lane >> 5;
  const int swz  = (q32 & 7) << 4;

  // staging decomposition
  const int g2   = (tid >> 4) & 3;   // 0..3
  const int n16  = tid & 15;         // 0..15
  const int dstg = wid * 16 + n16;   // 0..63

  const int bx   = blockIdx.x;
  const int h    = bx & 15;
  const int rest = bx >> 4;        // 0..31
  const int pp   = rest >> 2;      // 0..7
  const int jj   = rest & 3;       // 0..3
  const int LA   = 2 * pp + 2;     // tiles of small q-tile
  const int BND[5] = {0, 8, 17, 25, 34};
  const int tl = BND[jj], th = BND[jj + 1];

  const float SCALE = 1.44269504088896f / sqrtf((float)DD);
  const float* Kb = K + (size_t)h * DD;
  const float* Vb = V + (size_t)h * DD;

  uint4 kreg[4];
  uint2 vreg[2][4];

  for (int phase = 0; phase < 2; ++phase) {
    int qt, lo, hiT;
    if (phase == 0) { qt = pp;      lo = tl;               hiT = min(th, LA); }
    else            { qt = 15 - pp; lo = max(tl, LA) - LA; hiT = th - LA; }
    if (lo >= hiT) continue;

    const int qb = qt * QB;
    const int qw = qb + 32 * wid;      // wave's first q row
    const int qg = qw + q32;           // this lane's q row

    // ---- Q fragments (B operand): qf[ks] = Q[qg][16ks+8hi+0..7] * SCALE ----
    bf16x8 qf[8];
    {
      const float* qr = Q + ((size_t)qg * HH + h) * DD;
      #pragma unroll
      for (int ks = 0; ks < 8; ++ks) {
        float4 x = *(const float4*)&qr[16 * ks + 8 * hi];
        float4 y = *(const float4*)&qr[16 * ks + 8 * hi + 4];
        uint4 u;
        u.x = pk2(x.x * SCALE, x.y * SCALE);
        u.y = pk2(x.z * SCALE, x.w * SCALE);
        u.z = pk2(y.x * SCALE, y.y * SCALE);
        u.w = pk2(y.z * SCALE, y.w * SCALE);
        qf[ks] = __builtin_bit_cast(bf16x8, u);
      }
    }

    f32x16 acc[4];
    #pragma unroll
    for (int dt = 0; dt < 4; ++dt)
      #pragma unroll
      for (int e = 0; e < 16; ++e) acc[dt][e] = 0.f;
    float m = -1e30f, l = 0.f;

    // ---- prefetch tile lo (K coalesced float4; V 4-row column gather) ----
    {
      const int t0 = lo * KVB;
      #pragma unroll
      for (int it = 0; it < 4; ++it) {
        int e = tid + it * 256;
        int row = e >> 4, col = (e & 15) * 8;
        const float* src = &Kb[(size_t)(t0 + row) * HD + col];
        float4 a = *(const float4*)src;
        float4 b = *(const float4*)(src + 4);
        kreg[it].x = pk2(a.x, a.y); kreg[it].y = pk2(a.z, a.w);
        kreg[it].z = pk2(b.x, b.y); kreg[it].w = pk2(b.z, b.w);
      }
      #pragma unroll
      for (int half = 0; half < 2; ++half) {
        const int d = dstg + 64 * half;
        #pragma unroll
        for (int jv = 0; jv < 4; ++jv) {
          const int tt = 16 * jv + 4 * g2;
          const float* vp = &Vb[(size_t)(t0 + tt) * HD + d];
          vreg[half][jv].x = pk2(vp[0],      vp[HD]);
          vreg[half][jv].y = pk2(vp[2 * HD], vp[3 * HD]);
        }
      }
    }

    for (int itile = lo; itile < hiT; ++itile) {
      __syncthreads();   // previous tile's LDS fully consumed
      // ---- stage (pure swizzled stores, data already bf16) ----
      #pragma unroll
      for (int it = 0; it < 4; ++it) {
        int e = tid + it * 256;
        int row = e >> 4;
        *(uint4*)((char*)Klds + ((e * 16) ^ ((row & 7) << 4))) = kreg[it];
      }
      #pragma unroll
      for (int half = 0; half < 2; ++half) {
        const int d = dstg + 64 * half;
        #pragma unroll
        for (int jv = 0; jv < 4; ++jv) {
          const int tt = 16 * jv + 4 * g2;
          *(uint2*)((char*)VTlds + ((d * 128 + tt * 2) ^ ((d & 7) << 4))) = vreg[half][jv];
        }
      }
      __syncthreads();   // tile ready

      // ---- prefetch next tile ----
      if (itile + 1 < hiT) {
        const int t0n = (itile + 1) * KVB;
        #pragma unroll
        for (int it = 0; it < 4; ++it) {
          int e = tid + it * 256;
          int row = e >> 4, col = (e & 15) * 8;
          const float* src = &Kb[(size_t)(t0n + row) * HD + col];
          float4 a = *(const float4*)src;
          float4 b = *(const float4*)(src + 4);
          kreg[it].x = pk2(a.x, a.y); kreg[it].y = pk2(a.z, a.w);
          kreg[it].z = pk2(b.x, b.y); kreg[it].w = pk2(b.z, b.w);
        }
        #pragma unroll
        for (int half = 0; half < 2; ++half) {
          const int d = dstg + 64 * half;
          #pragma unroll
          for (int jv = 0; jv < 4; ++jv) {
            const int tt = 16 * jv + 4 * g2;
            const float* vp = &Vb[(size_t)(t0n + tt) * HD + d];
            vreg[half][jv].x = pk2(vp[0],      vp[HD]);
            vreg[half][jv].y = pk2(vp[2 * HD], vp[3 * HD]);
          }
        }
      }

      const int t0 = itile * KVB;

      // ---- QK^T swapped: s0 = S^T[t0..t0+31][q], s1 = S^T[t0+32..][q] ----
      f32x16 s0, s1;
      #pragma unroll
      for (int e = 0; e < 16; ++e) { s0[e] = 0.f; s1[e] = 0.f; }
      __builtin_amdgcn_s_setprio(1);
      #pragma unroll
      for (int ks = 0; ks < 8; ++ks) {
        bf16x8 a0 = *(const bf16x8*)((const char*)Klds +
                      ((q32 * 256 + 32 * ks + 16 * hi) ^ swz));
        s0 = __builtin_amdgcn_mfma_f32_32x32x16_bf16(a0, qf[ks], s0, 0, 0, 0);
      }
      #pragma unroll
      for (int ks = 0; ks < 8; ++ks) {
        bf16x8 a1 = *(const bf16x8*)((const char*)Klds +
                      (((q32 + 32) * 256 + 32 * ks + 16 * hi) ^ swz));
        s1 = __builtin_amdgcn_mfma_f32_32x32x16_bf16(a1, qf[ks], s1, 0, 0, 0);
      }
      __builtin_amdgcn_s_setprio(0);

      // ---- causal mask (lane holds t = t0 + 32*half + (e&3)+8*(e>>2)+4hi) ----
      if (t0 + KVB - 1 > qw) {
        #pragma unroll
        for (int e = 0; e < 16; ++e) {
          int tloc = (e & 3) + 8 * (e >> 2) + 4 * hi;
          if (t0 + tloc > qg)      s0[e] = -INFINITY;
          if (t0 + 32 + tloc > qg) s1[e] = -INFINITY;
        }
      }

      // ---- online softmax, fully in-register ----
      float mr = -1e30f;
      #pragma unroll
      for (int e = 0; e < 16; ++e) mr = fmaxf(mr, fmaxf(s0[e], s1[e]));
      mr = fmaxf(mr, __shfl_xor(mr, 32));
      float mn = fmaxf(m, mr);
      float corr = exp2f(m - mn);
      m = mn;
      float ps = 0.f;
      #pragma unroll
      for (int e = 0; e < 16; ++e) {
        float p0 = exp2f(s0[e] - m); s0[e] = p0; ps += p0;
        float p1 = exp2f(s1[e] - m); s1[e] = p1; ps += p1;
      }
      ps += __shfl_xor(ps, 32);
      l = l * corr + ps;
      #pragma unroll
      for (int dt = 0; dt < 4; ++dt)
        #pragma unroll
        for (int e = 0; e < 16; ++e) acc[dt][e] *= corr;

      // ---- P -> bf16 B-fragments (cvt_pk pairs + lane<->lane+32 exchange) ----
      uint4 paf[4];
      #pragma unroll
      for (int tk = 0; tk < 4; ++tk) {
        float p0,p1,p2,p3,p4,p5,p6,p7;
        if (tk == 0) { p0=s0[0];p1=s0[1];p2=s0[2];p3=s0[3];p4=s0[4];p5=s0[5];p6=s0[6];p7=s0[7]; }
        else if (tk == 1) { p0=s0[8];p1=s0[9];p2=s0[10];p3=s0[11];p4=s0[12];p5=s0[13];p6=s0[14];p7=s0[15]; }
        else if (tk == 2) { p0=s1[0];p1=s1[1];p2=s1[2];p3=s1[3];p4=s1[4];p5=s1[5];p6=s1[6];p7=s1[7]; }
        else { p0=s1[8];p1=s1[9];p2=s1[10];p3=s1[11];p4=s1[12];p5=s1[13];p6=s1[14];p7=s1[15]; }
        uint A0 = pk2(p0, p1), A1 = pk2(p2, p3);
        uint B0 = pk2(p4, p5), B1 = pk2(p6, p7);
        uint x0 = hi ? A0 : B0, x1 = hi ? A1 : B1;
        uint r0 = (uint)__shfl_xor((int)x0, 32);
        uint r1 = (uint)__shfl_xor((int)x1, 32);
        paf[tk].x = hi ? r0 : A0;
        paf[tk].y = hi ? r1 : A1;
        paf[tk].z = hi ? B0 : r0;
        paf[tk].w = hi ? B1 : r1;
      }

      // ---- PV: acc[dt] = O^T[d-tile][q] += V^T x P^T ----
      __builtin_amdgcn_s_setprio(1);
      #pragma unroll
      for (int dt = 0; dt < 4; ++dt) {
        #pragma unroll
        for (int tk = 0; tk < 4; ++tk) {
          bf16x8 va = *(const bf16x8*)((const char*)VTlds +
                        (((dt * 32 + q32) * 128 + 32 * tk + 16 * hi) ^ swz));
          bf16x8 pb = __builtin_bit_cast(bf16x8, paf[tk]);
          acc[dt] = __builtin_amdgcn_mfma_f32_32x32x16_bf16(va, pb, acc[dt], 0, 0, 0);
        }
      }
      __builtin_amdgcn_s_setprio(0);
    }

    // ---- partial epilogue (unnormalized, bf16) ----
    const int slot = (((h * 8 + pp) * 4 + jj) * 2) + phase;
    ushort* po = PO + (size_t)slot * (QB * DD);
    const int row = 32 * wid + q32;
    #pragma unroll
    for (int dt = 0; dt < 4; ++dt) {
      #pragma unroll
      for (int rq = 0; rq < 4; ++rq) {
        int d = 32 * dt + 8 * rq + 4 * hi;
        uint2 w;
        w.x = pk2(acc[dt][4 * rq + 0], acc[dt][4 * rq + 1]);
        w.y = pk2(acc[dt][4 * rq + 2], acc[dt][4 * rq + 3]);
        *(uint2*)&po[row * DD + d] = w;
      }
    }
    if (hi == 0) {
      PM[(size_t)slot * QB + row] = m;
      PL[(size_t)slot * QB + row] = l;
    }
  }
}

// ---------------------------------------------------------------------------
// Merge 1-4 partials per (h, qt).
// ---------------------------------------------------------------------------
__global__ __launch_bounds__(256, 4)
void attn_merge(const ushort* __restrict__ PO, const float* __restrict__ PM,
                const float* __restrict__ PL, float* __restrict__ O) {
  const int bx  = blockIdx.x;      // 256 = 16 qt * 16 h
  const int h   = bx & 15;
  const int qt  = bx >> 4;
  const int tid = threadIdx.x;
  const int r   = tid >> 1;        // 0..127
  const int dh  = (tid & 1) * 64;

  const int BND[5] = {0, 8, 17, 25, 34};
  const int pp    = (qt < 8) ? qt : (15 - qt);
  const int phase = (qt < 8) ? 0 : 1;
  const int LA    = 2 * pp + 2;

  float mv[4], lv[4];
  float M = -1e30f;
  #pragma unroll
  for (int jj = 0; jj < 4; ++jj) {
    bool inc = (phase == 0) ? (BND[jj] < LA) : (BND[jj + 1] > LA);
    int slot = (((h * 8 + pp) * 4 + jj) * 2) + phase;
    mv[jj] = inc ? PM[(size_t)slot * QB + r] : -1e30f;
    lv[jj] = inc ? PL[(size_t)slot * QB + r] : 0.f;
    M = fmaxf(M, mv[jj]);
  }
  float L = 0.f;
  float o[64];
  #pragma unroll
  for (int k2 = 0; k2 < 64; ++k2) o[k2] = 0.f;
  #pragma unroll
  for (int jj = 0; jj < 4; ++jj) {
    bool inc = (phase == 0) ? (BND[jj] < LA) : (BND[jj + 1] > LA);
    if (!inc) continue;
    int slot = (((h * 8 + pp) * 4 + jj) * 2) + phase;
    float w = exp2f(mv[jj] - M);
    L += lv[jj] * w;
    const ushort* src = PO + (size_t)slot * (QB * DD) + r * DD + dh;
    #pragma unroll
    for (int k4 = 0; k4 < 16; ++k4) {
      ushort4 u = *(const ushort4*)&src[4 * k4];
      o[4*k4+0] += bf2f(u.x) * w;
      o[4*k4+1] += bf2f(u.y) * w;
      o[4*k4+2] += bf2f(u.z) * w;
      o[4*k4+3] += bf2f(u.w) * w;
    }
  }
  float inv = 1.0f / L;
  float* op = O + ((size_t)(qt * QB + r) * HH + h) * DD + dh;
  #pragma unroll
  for (int k4 = 0; k4 < 16; ++k4) {
    float4 x = make_float4(o[4*k4]*inv, o[4*k4+1]*inv, o[4*k4+2]*inv, o[4*k4+3]*inv);
    *(float4*)&op[4 * k4] = x;
  }
}

extern "C" void kernel_launch(void* const* d_in, const int* in_sizes, int n_in,
                              void* d_out, int out_size, void* d_ws, size_t ws_size,
                              hipStream_t stream) {
  const float* Q = (const float*)d_in[0];
  const float* K = (const float*)d_in[1];
  const float* V = (const float*)d_in[2];
  float* O = (float*)d_out;

  const size_t po_elems = (size_t)1024 * QB * DD;        // bf16: 32 MB
  ushort* PO = (ushort*)d_ws;
  float*  PM = (float*)(PO + po_elems);                  // 1024*128 f32
  float*  PL = PM + (size_t)1024 * QB;

  attn_fwd<<<dim3(512), 256, 0, stream>>>(Q, K, V, PO, PM, PL);
  attn_merge<<<dim3(256), 256, 0, stream>>>(PO, PM, PL, O);
}

// Round 9
// 65.037 us; speedup vs baseline: 1.4822x; 1.0732x over previous
//
#include <hip/hip_runtime.h>
#include <hip/hip_bf16.h>
#include <math.h>

#define SS 2048
#define HH 16
#define DD 128
#define HD (HH*DD)
#define QB 128          // q-rows per block (4 waves x 32)
#define KVB 64          // kv-tile

typedef __attribute__((ext_vector_type(8))) short bf16x8;
typedef __attribute__((ext_vector_type(16))) float f32x16;

__device__ __forceinline__ ushort f2bf(float f) {
  __hip_bfloat16 h = __float2bfloat16(f);
  return __builtin_bit_cast(ushort, h);
}
__device__ __forceinline__ uint pk2(float a, float b) {   // low=a, high=b
  return ((uint)f2bf(b) << 16) | (uint)f2bf(a);
}
__device__ __forceinline__ float bf2f(ushort u) {
  uint x = ((uint)u) << 16;
  return __builtin_bit_cast(float, x);
}

// ---------------------------------------------------------------------------
// Partial flash attention. Job = (h, pp, jj): pair (qt=pp, qt=15-pp), tiles
// split at {0,8,17,25,34}. 32x32 MFMA, swapped QK^T (S^T), in-register P,
// O^T accumulator, swizzled double-buffered LDS (1 barrier/tile), defer-max.
// ---------------------------------------------------------------------------
__global__ __launch_bounds__(256, 2)
void attn_fwd(const float* __restrict__ Q, const float* __restrict__ K,
              const float* __restrict__ V,
              ushort* __restrict__ PO, float* __restrict__ PM,
              float* __restrict__ PL) {
  __shared__ alignas(16) ushort Klds[2][KVB * DD];    // 2 x 16 KB, swizzled
  __shared__ alignas(16) ushort VTlds[2][DD * KVB];   // 2 x 16 KB, swizzled

  const int tid  = threadIdx.x;
  const int lane = tid & 63;
  const int wid  = tid >> 6;       // 0..3
  const int q32  = lane & 31;
  const int hi   = lane >> 5;
  const int swz  = (q32 & 7) << 4;

  // staging decomposition
  const int g2   = (tid >> 4) & 3;   // 0..3
  const int n16  = tid & 15;         // 0..15
  const int dstg = wid * 16 + n16;   // 0..63

  const int bx   = blockIdx.x;
  const int h    = bx & 15;
  const int rest = bx >> 4;        // 0..31
  const int pp   = rest >> 2;      // 0..7
  const int jj   = rest & 3;       // 0..3
  const int LA   = 2 * pp + 2;     // tiles of small q-tile
  const int BND[5] = {0, 8, 17, 25, 34};
  const int tl = BND[jj], th = BND[jj + 1];

  const float SCALE = 1.44269504088896f / sqrtf((float)DD);
  const float* Kb = K + (size_t)h * DD;
  const float* Vb = V + (size_t)h * DD;

  uint4 kreg[4];
  uint2 vreg[2][4];

  auto loadt = [&](int t0) {
    #pragma unroll
    for (int it = 0; it < 4; ++it) {
      int e = tid + it * 256;
      int row = e >> 4, col = (e & 15) * 8;
      const float* src = &Kb[(size_t)(t0 + row) * HD + col];
      float4 a = *(const float4*)src;
      float4 b = *(const float4*)(src + 4);
      kreg[it].x = pk2(a.x, a.y); kreg[it].y = pk2(a.z, a.w);
      kreg[it].z = pk2(b.x, b.y); kreg[it].w = pk2(b.z, b.w);
    }
    #pragma unroll
    for (int half = 0; half < 2; ++half) {
      const int d = dstg + 64 * half;
      #pragma unroll
      for (int jv = 0; jv < 4; ++jv) {
        const int tt = 16 * jv + 4 * g2;
        const float* vp = &Vb[(size_t)(t0 + tt) * HD + d];
        vreg[half][jv].x = pk2(vp[0],      vp[HD]);
        vreg[half][jv].y = pk2(vp[2 * HD], vp[3 * HD]);
      }
    }
  };
  auto staget = [&](int b) {
    #pragma unroll
    for (int it = 0; it < 4; ++it) {
      int e = tid + it * 256;
      int row = e >> 4;
      *(uint4*)((char*)&Klds[b][0] + ((e * 16) ^ ((row & 7) << 4))) = kreg[it];
    }
    #pragma unroll
    for (int half = 0; half < 2; ++half) {
      const int d = dstg + 64 * half;
      #pragma unroll
      for (int jv = 0; jv < 4; ++jv) {
        const int tt = 16 * jv + 4 * g2;
        *(uint2*)((char*)&VTlds[b][0] + ((d * 128 + tt * 2) ^ ((d & 7) << 4))) = vreg[half][jv];
      }
    }
  };

  for (int phase = 0; phase < 2; ++phase) {
    int qt, lo, hiT;
    if (phase == 0) { qt = pp;      lo = tl;               hiT = min(th, LA); }
    else            { qt = 15 - pp; lo = max(tl, LA) - LA; hiT = th - LA; }
    if (lo >= hiT) continue;

    const int qb = qt * QB;
    const int qw = qb + 32 * wid;      // wave's first q row
    const int qg = qw + q32;           // this lane's q row

    // ---- Q fragments (B operand): qf[ks] = Q[qg][16ks+8hi+0..7] * SCALE ----
    bf16x8 qf[8];
    {
      const float* qr = Q + ((size_t)qg * HH + h) * DD;
      #pragma unroll
      for (int ks = 0; ks < 8; ++ks) {
        float4 x = *(const float4*)&qr[16 * ks + 8 * hi];
        float4 y = *(const float4*)&qr[16 * ks + 8 * hi + 4];
        uint4 u;
        u.x = pk2(x.x * SCALE, x.y * SCALE);
        u.y = pk2(x.z * SCALE, x.w * SCALE);
        u.z = pk2(y.x * SCALE, y.y * SCALE);
        u.w = pk2(y.z * SCALE, y.w * SCALE);
        qf[ks] = __builtin_bit_cast(bf16x8, u);
      }
    }

    f32x16 acc[4];
    #pragma unroll
    for (int dt = 0; dt < 4; ++dt)
      #pragma unroll
      for (int e = 0; e < 16; ++e) acc[dt][e] = 0.f;
    float m = -1e30f, l = 0.f;

    // ---- prologue: tile lo -> regs -> buf0 ----
    loadt(lo * KVB);
    __syncthreads();               // prior phase's readers done with buf0
    staget(0);
    int cur = 0;

    for (int itile = lo; itile < hiT; ++itile) {
      __syncthreads();             // buf[cur] staged & visible; buf[cur^1] free
      const bool more = (itile + 1 < hiT);
      if (more) loadt((itile + 1) * KVB);

      const int t0 = itile * KVB;
      const char* Kc = (const char*)&Klds[cur][0];
      const char* Vc = (const char*)&VTlds[cur][0];

      // ---- QK^T swapped: s0 = S^T[t0..t0+31][q], s1 = S^T[t0+32..][q] ----
      f32x16 s0, s1;
      #pragma unroll
      for (int e = 0; e < 16; ++e) { s0[e] = 0.f; s1[e] = 0.f; }
      __builtin_amdgcn_s_setprio(1);
      #pragma unroll
      for (int ks = 0; ks < 8; ++ks) {
        bf16x8 a0 = *(const bf16x8*)(Kc + ((q32 * 256 + 32 * ks + 16 * hi) ^ swz));
        s0 = __builtin_amdgcn_mfma_f32_32x32x16_bf16(a0, qf[ks], s0, 0, 0, 0);
      }
      #pragma unroll
      for (int ks = 0; ks < 8; ++ks) {
        bf16x8 a1 = *(const bf16x8*)(Kc + (((q32 + 32) * 256 + 32 * ks + 16 * hi) ^ swz));
        s1 = __builtin_amdgcn_mfma_f32_32x32x16_bf16(a1, qf[ks], s1, 0, 0, 0);
      }
      __builtin_amdgcn_s_setprio(0);

      // ---- causal mask ----
      if (t0 + KVB - 1 > qw) {
        #pragma unroll
        for (int e = 0; e < 16; ++e) {
          int tloc = (e & 3) + 8 * (e >> 2) + 4 * hi;
          if (t0 + tloc > qg)      s0[e] = -INFINITY;
          if (t0 + 32 + tloc > qg) s1[e] = -INFINITY;
        }
      }

      // ---- online softmax, in-register, tree reductions + defer-max ----
      float tmx[8];
      #pragma unroll
      for (int e = 0; e < 8; ++e)
        tmx[e] = fmaxf(fmaxf(s0[e], s0[e + 8]), fmaxf(s1[e], s1[e + 8]));
      #pragma unroll
      for (int st = 4; st >= 1; st >>= 1)
        #pragma unroll
        for (int e = 0; e < st; ++e) tmx[e] = fmaxf(tmx[e], tmx[e + st]);
      float mr = fmaxf(tmx[0], __shfl_xor(tmx[0], 32));

      if (!__all(mr <= m + 8.0f)) {
        float mn = fmaxf(m, mr);
        float corr = exp2f(m - mn);
        m = mn;
        l *= corr;
        #pragma unroll
        for (int dt = 0; dt < 4; ++dt)
          #pragma unroll
          for (int e = 0; e < 16; ++e) acc[dt][e] *= corr;
      }

      float ts[8];
      #pragma unroll
      for (int e = 0; e < 8; ++e) ts[e] = 0.f;
      #pragma unroll
      for (int e = 0; e < 16; ++e) {
        float p0 = exp2f(s0[e] - m); s0[e] = p0;
        float p1 = exp2f(s1[e] - m); s1[e] = p1;
        ts[e & 7] += p0 + p1;
      }
      #pragma unroll
      for (int st = 4; st >= 1; st >>= 1)
        #pragma unroll
        for (int e = 0; e < st; ++e) ts[e] += ts[e + st];
      float ps = ts[0] + __shfl_xor(ts[0], 32);
      l += ps;

      // ---- P -> bf16 B-fragments (cvt_pk pairs + lane<->lane+32 exchange) ----
      uint4 paf[4];
      #pragma unroll
      for (int tk = 0; tk < 4; ++tk) {
        float p0,p1,p2,p3,p4,p5,p6,p7;
        if (tk == 0) { p0=s0[0];p1=s0[1];p2=s0[2];p3=s0[3];p4=s0[4];p5=s0[5];p6=s0[6];p7=s0[7]; }
        else if (tk == 1) { p0=s0[8];p1=s0[9];p2=s0[10];p3=s0[11];p4=s0[12];p5=s0[13];p6=s0[14];p7=s0[15]; }
        else if (tk == 2) { p0=s1[0];p1=s1[1];p2=s1[2];p3=s1[3];p4=s1[4];p5=s1[5];p6=s1[6];p7=s1[7]; }
        else { p0=s1[8];p1=s1[9];p2=s1[10];p3=s1[11];p4=s1[12];p5=s1[13];p6=s1[14];p7=s1[15]; }
        uint A0 = pk2(p0, p1), A1 = pk2(p2, p3);
        uint B0 = pk2(p4, p5), B1 = pk2(p6, p7);
        uint x0 = hi ? A0 : B0, x1 = hi ? A1 : B1;
        uint r0 = (uint)__shfl_xor((int)x0, 32);
        uint r1 = (uint)__shfl_xor((int)x1, 32);
        paf[tk].x = hi ? r0 : A0;
        paf[tk].y = hi ? r1 : A1;
        paf[tk].z = hi ? B0 : r0;
        paf[tk].w = hi ? B1 : r1;
      }

      // ---- PV: acc[dt] = O^T[d-tile][q] += V^T x P^T ----
      __builtin_amdgcn_s_setprio(1);
      #pragma unroll
      for (int dt = 0; dt < 4; ++dt) {
        #pragma unroll
        for (int tk = 0; tk < 4; ++tk) {
          bf16x8 va = *(const bf16x8*)(Vc +
                        (((dt * 32 + q32) * 128 + 32 * tk + 16 * hi) ^ swz));
          bf16x8 pb = __builtin_bit_cast(bf16x8, paf[tk]);
          acc[dt] = __builtin_amdgcn_mfma_f32_32x32x16_bf16(va, pb, acc[dt], 0, 0, 0);
        }
      }
      __builtin_amdgcn_s_setprio(0);

      // ---- stage tile t+1 into the other buffer ----
      if (more) staget(cur ^ 1);
      cur ^= 1;
    }

    // ---- partial epilogue (unnormalized, bf16) ----
    const int slot = (((h * 8 + pp) * 4 + jj) * 2) + phase;
    ushort* po = PO + (size_t)slot * (QB * DD);
    const int row = 32 * wid + q32;
    #pragma unroll
    for (int dt = 0; dt < 4; ++dt) {
      #pragma unroll
      for (int rq = 0; rq < 4; ++rq) {
        int d = 32 * dt + 8 * rq + 4 * hi;
        uint2 w;
        w.x = pk2(acc[dt][4 * rq + 0], acc[dt][4 * rq + 1]);
        w.y = pk2(acc[dt][4 * rq + 2], acc[dt][4 * rq + 3]);
        *(uint2*)&po[row * DD + d] = w;
      }
    }
    if (hi == 0) {
      PM[(size_t)slot * QB + row] = m;
      PL[(size_t)slot * QB + row] = l;
    }
  }
}

// ---------------------------------------------------------------------------
// Merge 1-4 partials per (h, qt).
// ---------------------------------------------------------------------------
__global__ __launch_bounds__(256, 4)
void attn_merge(const ushort* __restrict__ PO, const float* __restrict__ PM,
                const float* __restrict__ PL, float* __restrict__ O) {
  const int bx  = blockIdx.x;      // 256 = 16 qt * 16 h
  const int h   = bx & 15;
  const int qt  = bx >> 4;
  const int tid = threadIdx.x;
  const int r   = tid >> 1;        // 0..127
  const int dh  = (tid & 1) * 64;

  const int BND[5] = {0, 8, 17, 25, 34};
  const int pp    = (qt < 8) ? qt : (15 - qt);
  const int phase = (qt < 8) ? 0 : 1;
  const int LA    = 2 * pp + 2;

  float mv[4], lv[4];
  float M = -1e30f;
  #pragma unroll
  for (int jj = 0; jj < 4; ++jj) {
    bool inc = (phase == 0) ? (BND[jj] < LA) : (BND[jj + 1] > LA);
    int slot = (((h * 8 + pp) * 4 + jj) * 2) + phase;
    mv[jj] = inc ? PM[(size_t)slot * QB + r] : -1e30f;
    lv[jj] = inc ? PL[(size_t)slot * QB + r] : 0.f;
    M = fmaxf(M, mv[jj]);
  }
  float L = 0.f;
  float o[64];
  #pragma unroll
  for (int k2 = 0; k2 < 64; ++k2) o[k2] = 0.f;
  #pragma unroll
  for (int jj = 0; jj < 4; ++jj) {
    bool inc = (phase == 0) ? (BND[jj] < LA) : (BND[jj + 1] > LA);
    if (!inc) continue;
    int slot = (((h * 8 + pp) * 4 + jj) * 2) + phase;
    float w = exp2f(mv[jj] - M);
    L += lv[jj] * w;
    const ushort* src = PO + (size_t)slot * (QB * DD) + r * DD + dh;
    #pragma unroll
    for (int k4 = 0; k4 < 16; ++k4) {
      ushort4 u = *(const ushort4*)&src[4 * k4];
      o[4*k4+0] += bf2f(u.x) * w;
      o[4*k4+1] += bf2f(u.y) * w;
      o[4*k4+2] += bf2f(u.z) * w;
      o[4*k4+3] += bf2f(u.w) * w;
    }
  }
  float inv = 1.0f / L;
  float* op = O + ((size_t)(qt * QB + r) * HH + h) * DD + dh;
  #pragma unroll
  for (int k4 = 0; k4 < 16; ++k4) {
    float4 x = make_float4(o[4*k4]*inv, o[4*k4+1]*inv, o[4*k4+2]*inv, o[4*k4+3]*inv);
    *(float4*)&op[4 * k4] = x;
  }
}

extern "C" void kernel_launch(void* const* d_in, const int* in_sizes, int n_in,
                              void* d_out, int out_size, void* d_ws, size_t ws_size,
                              hipStream_t stream) {
  const float* Q = (const float*)d_in[0];
  const float* K = (const float*)d_in[1];
  const float* V = (const float*)d_in[2];
  float* O = (float*)d_out;

  const size_t po_elems = (size_t)1024 * QB * DD;        // bf16: 32 MB
  ushort* PO = (ushort*)d_ws;
  float*  PM = (float*)(PO + po_elems);                  // 1024*128 f32
  float*  PL = PM + (size_t)1024 * QB;

  attn_fwd<<<dim3(512), 256, 0, stream>>>(Q, K, V, PO, PM, PL);
  attn_merge<<<dim3(256), 256, 0, stream>>>(PO, PM, PL, O);
}

// Round 10
// 64.570 us; speedup vs baseline: 1.4929x; 1.0072x over previous
//
#include <hip/hip_runtime.h>
#include <hip/hip_bf16.h>
#include <math.h>

#define SS 2048
#define HH 16
#define DD 128
#define HD (HH*DD)
#define QB 128          // q-rows per block (4 waves x 32)
#define KVB 64          // kv-tile

typedef __attribute__((ext_vector_type(8))) short bf16x8;
typedef __attribute__((ext_vector_type(16))) float f32x16;

__device__ __forceinline__ ushort f2bf(float f) {
  __hip_bfloat16 h = __float2bfloat16(f);
  return __builtin_bit_cast(ushort, h);
}
__device__ __forceinline__ uint pk2(float a, float b) {   // low=a, high=b
  return ((uint)f2bf(b) << 16) | (uint)f2bf(a);
}
__device__ __forceinline__ float bf2f(ushort u) {
  uint x = ((uint)u) << 16;
  return __builtin_bit_cast(float, x);
}

// ---------------------------------------------------------------------------
// Partial flash attention. Job = (h, pp, jj): pair (qt=pp, qt=15-pp), tiles
// split at {0,8,17,25,34}. 32x32 MFMA, swapped QK^T (S^T), in-register P,
// O^T accumulator, double-buffered LDS (1 barrier/tile), defer-max.
// Swizzles: K rows (256B): ^(row&15)<<4  -> 2-way banks on read.
//           V rows (128B): ^((d&7)<<4)^((d&8)<<1) -> 2-way banks on read.
// ---------------------------------------------------------------------------
__global__ __launch_bounds__(256, 2)
void attn_fwd(const float* __restrict__ Q, const float* __restrict__ K,
              const float* __restrict__ V,
              ushort* __restrict__ PO, float* __restrict__ PM,
              float* __restrict__ PL) {
  __shared__ alignas(16) ushort Klds[2][KVB * DD];    // 2 x 16 KB
  __shared__ alignas(16) ushort VTlds[2][DD * KVB];   // 2 x 16 KB

  const int tid  = threadIdx.x;
  const int lane = tid & 63;
  const int wid  = tid >> 6;       // 0..3
  const int q32  = lane & 31;
  const int hi   = lane >> 5;
  const int kxk  = (q32 & 15) << 4;                        // K read swizzle
  const int kxv  = ((q32 & 7) << 4) ^ ((q32 & 8) << 1);    // V read swizzle

  // staging decomposition
  const int g2   = (tid >> 4) & 3;   // 0..3
  const int n16  = tid & 15;         // 0..15
  const int dstg = wid * 16 + n16;   // 0..63
  const int swv  = ((dstg & 7) << 4) ^ ((dstg & 8) << 1);  // V write swizzle

  const int bx   = blockIdx.x;
  const int h    = bx & 15;
  const int rest = bx >> 4;        // 0..31
  const int pp   = rest >> 2;      // 0..7
  const int jj   = rest & 3;       // 0..3
  const int LA   = 2 * pp + 2;     // tiles of small q-tile
  const int BND[5] = {0, 8, 17, 25, 34};
  const int tl = BND[jj], th = BND[jj + 1];

  const float SCALE = 1.44269504088896f / sqrtf((float)DD);
  const float* Kb = K + (size_t)h * DD;
  const float* Vb = V + (size_t)h * DD;

  uint4 kreg[4];
  uint2 vreg[2][4];

  auto loadt = [&](int t0) {
    #pragma unroll
    for (int it = 0; it < 4; ++it) {
      int e = tid + it * 256;
      int row = e >> 4, col = (e & 15) * 8;
      const float* src = &Kb[(size_t)(t0 + row) * HD + col];
      float4 a = *(const float4*)src;
      float4 b = *(const float4*)(src + 4);
      kreg[it].x = pk2(a.x, a.y); kreg[it].y = pk2(a.z, a.w);
      kreg[it].z = pk2(b.x, b.y); kreg[it].w = pk2(b.z, b.w);
    }
    #pragma unroll
    for (int half = 0; half < 2; ++half) {
      const int d = dstg + 64 * half;
      #pragma unroll
      for (int jv = 0; jv < 4; ++jv) {
        const int tt = 16 * jv + 4 * g2;
        const float* vp = &Vb[(size_t)(t0 + tt) * HD + d];
        vreg[half][jv].x = pk2(vp[0],      vp[HD]);
        vreg[half][jv].y = pk2(vp[2 * HD], vp[3 * HD]);
      }
    }
  };
  auto staget = [&](int b) {
    #pragma unroll
    for (int it = 0; it < 4; ++it) {
      int e = tid + it * 256;
      *(uint4*)((char*)&Klds[b][0] + ((e * 16) ^ (e & 0xF0))) = kreg[it];
    }
    #pragma unroll
    for (int half = 0; half < 2; ++half) {
      const int d = dstg + 64 * half;
      #pragma unroll
      for (int jv = 0; jv < 4; ++jv) {
        const int tt = 16 * jv + 4 * g2;
        *(uint2*)((char*)&VTlds[b][0] + ((d * 128 + tt * 2) ^ swv)) = vreg[half][jv];
      }
    }
  };

  for (int phase = 0; phase < 2; ++phase) {
    int qt, lo, hiT;
    if (phase == 0) { qt = pp;      lo = tl;               hiT = min(th, LA); }
    else            { qt = 15 - pp; lo = max(tl, LA) - LA; hiT = th - LA; }
    if (lo >= hiT) continue;

    const int qb = qt * QB;
    const int qw = qb + 32 * wid;      // wave's first q row
    const int qg = qw + q32;           // this lane's q row

    // ---- Q fragments (B operand): qf[ks] = Q[qg][16ks+8hi+0..7] * SCALE ----
    bf16x8 qf[8];
    {
      const float* qr = Q + ((size_t)qg * HH + h) * DD;
      #pragma unroll
      for (int ks = 0; ks < 8; ++ks) {
        float4 x = *(const float4*)&qr[16 * ks + 8 * hi];
        float4 y = *(const float4*)&qr[16 * ks + 8 * hi + 4];
        uint4 u;
        u.x = pk2(x.x * SCALE, x.y * SCALE);
        u.y = pk2(x.z * SCALE, x.w * SCALE);
        u.z = pk2(y.x * SCALE, y.y * SCALE);
        u.w = pk2(y.z * SCALE, y.w * SCALE);
        qf[ks] = __builtin_bit_cast(bf16x8, u);
      }
    }

    f32x16 acc[4];
    #pragma unroll
    for (int dt = 0; dt < 4; ++dt)
      #pragma unroll
      for (int e = 0; e < 16; ++e) acc[dt][e] = 0.f;
    float m = -1e30f, l = 0.f;

    // ---- prologue: tile lo -> regs -> buf0 ----
    loadt(lo * KVB);
    __syncthreads();               // prior phase's readers done with buf0
    staget(0);
    int cur = 0;

    for (int itile = lo; itile < hiT; ++itile) {
      __syncthreads();             // buf[cur] staged & visible; buf[cur^1] free
      const bool more = (itile + 1 < hiT);
      if (more) loadt((itile + 1) * KVB);

      const int t0 = itile * KVB;
      const char* Kc = (const char*)&Klds[cur][0];
      const char* Vc = (const char*)&VTlds[cur][0];

      // ---- QK^T swapped, s0/s1 interleaved (dep distance 2) ----
      f32x16 s0, s1;
      #pragma unroll
      for (int e = 0; e < 16; ++e) { s0[e] = 0.f; s1[e] = 0.f; }
      __builtin_amdgcn_s_setprio(1);
      #pragma unroll
      for (int ks = 0; ks < 8; ++ks) {
        bf16x8 a0 = *(const bf16x8*)(Kc + ((q32 * 256 + 32 * ks + 16 * hi) ^ kxk));
        s0 = __builtin_amdgcn_mfma_f32_32x32x16_bf16(a0, qf[ks], s0, 0, 0, 0);
        bf16x8 a1 = *(const bf16x8*)(Kc + (((q32 + 32) * 256 + 32 * ks + 16 * hi) ^ kxk));
        s1 = __builtin_amdgcn_mfma_f32_32x32x16_bf16(a1, qf[ks], s1, 0, 0, 0);
      }
      __builtin_amdgcn_s_setprio(0);

      // ---- causal mask ----
      if (t0 + KVB - 1 > qw) {
        #pragma unroll
        for (int e = 0; e < 16; ++e) {
          int tloc = (e & 3) + 8 * (e >> 2) + 4 * hi;
          if (t0 + tloc > qg)      s0[e] = -INFINITY;
          if (t0 + 32 + tloc > qg) s1[e] = -INFINITY;
        }
      }

      // ---- online softmax, in-register, tree reductions + defer-max ----
      float tmx[8];
      #pragma unroll
      for (int e = 0; e < 8; ++e)
        tmx[e] = fmaxf(fmaxf(s0[e], s0[e + 8]), fmaxf(s1[e], s1[e + 8]));
      #pragma unroll
      for (int st = 4; st >= 1; st >>= 1)
        #pragma unroll
        for (int e = 0; e < st; ++e) tmx[e] = fmaxf(tmx[e], tmx[e + st]);
      float mr = fmaxf(tmx[0], __shfl_xor(tmx[0], 32));

      if (!__all(mr <= m + 8.0f)) {
        float mn = fmaxf(m, mr);
        float corr = exp2f(m - mn);
        m = mn;
        l *= corr;
        #pragma unroll
        for (int dt = 0; dt < 4; ++dt)
          #pragma unroll
          for (int e = 0; e < 16; ++e) acc[dt][e] *= corr;
      }

      float ts[8];
      #pragma unroll
      for (int e = 0; e < 8; ++e) ts[e] = 0.f;
      #pragma unroll
      for (int e = 0; e < 16; ++e) {
        float p0 = exp2f(s0[e] - m); s0[e] = p0;
        float p1 = exp2f(s1[e] - m); s1[e] = p1;
        ts[e & 7] += p0 + p1;
      }
      #pragma unroll
      for (int st = 4; st >= 1; st >>= 1)
        #pragma unroll
        for (int e = 0; e < st; ++e) ts[e] += ts[e + st];
      float ps = ts[0] + __shfl_xor(ts[0], 32);
      l += ps;

      // ---- P -> bf16 B-fragments (cvt_pk pairs + lane<->lane+32 exchange) ----
      uint4 paf[4];
      #pragma unroll
      for (int tk = 0; tk < 4; ++tk) {
        float p0,p1,p2,p3,p4,p5,p6,p7;
        if (tk == 0) { p0=s0[0];p1=s0[1];p2=s0[2];p3=s0[3];p4=s0[4];p5=s0[5];p6=s0[6];p7=s0[7]; }
        else if (tk == 1) { p0=s0[8];p1=s0[9];p2=s0[10];p3=s0[11];p4=s0[12];p5=s0[13];p6=s0[14];p7=s0[15]; }
        else if (tk == 2) { p0=s1[0];p1=s1[1];p2=s1[2];p3=s1[3];p4=s1[4];p5=s1[5];p6=s1[6];p7=s1[7]; }
        else { p0=s1[8];p1=s1[9];p2=s1[10];p3=s1[11];p4=s1[12];p5=s1[13];p6=s1[14];p7=s1[15]; }
        uint A0 = pk2(p0, p1), A1 = pk2(p2, p3);
        uint B0 = pk2(p4, p5), B1 = pk2(p6, p7);
        uint x0 = hi ? A0 : B0, x1 = hi ? A1 : B1;
        uint r0 = (uint)__shfl_xor((int)x0, 32);
        uint r1 = (uint)__shfl_xor((int)x1, 32);
        paf[tk].x = hi ? r0 : A0;
        paf[tk].y = hi ? r1 : A1;
        paf[tk].z = hi ? B0 : r0;
        paf[tk].w = hi ? B1 : r1;
      }

      // ---- stage tile t+1 before PV (barrier then gated by PV only) ----
      if (more) staget(cur ^ 1);

      // ---- PV: tk outer / dt inner (dep distance 4) ----
      __builtin_amdgcn_s_setprio(1);
      #pragma unroll
      for (int tk = 0; tk < 4; ++tk) {
        bf16x8 pb = __builtin_bit_cast(bf16x8, paf[tk]);
        #pragma unroll
        for (int dt = 0; dt < 4; ++dt) {
          bf16x8 va = *(const bf16x8*)(Vc +
                        (((dt * 32 + q32) * 128 + 32 * tk + 16 * hi) ^ kxv));
          acc[dt] = __builtin_amdgcn_mfma_f32_32x32x16_bf16(va, pb, acc[dt], 0, 0, 0);
        }
      }
      __builtin_amdgcn_s_setprio(0);

      cur ^= 1;
    }

    // ---- partial epilogue (unnormalized, bf16) ----
    const int slot = (((h * 8 + pp) * 4 + jj) * 2) + phase;
    ushort* po = PO + (size_t)slot * (QB * DD);
    const int row = 32 * wid + q32;
    #pragma unroll
    for (int dt = 0; dt < 4; ++dt) {
      #pragma unroll
      for (int rq = 0; rq < 4; ++rq) {
        int d = 32 * dt + 8 * rq + 4 * hi;
        uint2 w;
        w.x = pk2(acc[dt][4 * rq + 0], acc[dt][4 * rq + 1]);
        w.y = pk2(acc[dt][4 * rq + 2], acc[dt][4 * rq + 3]);
        *(uint2*)&po[row * DD + d] = w;
      }
    }
    if (hi == 0) {
      PM[(size_t)slot * QB + row] = m;
      PL[(size_t)slot * QB + row] = l;
    }
  }
}

// ---------------------------------------------------------------------------
// Merge 1-4 partials per (h, qt).
// ---------------------------------------------------------------------------
__global__ __launch_bounds__(256, 4)
void attn_merge(const ushort* __restrict__ PO, const float* __restrict__ PM,
                const float* __restrict__ PL, float* __restrict__ O) {
  const int bx  = blockIdx.x;      // 256 = 16 qt * 16 h
  const int h   = bx & 15;
  const int qt  = bx >> 4;
  const int tid = threadIdx.x;
  const int r   = tid >> 1;        // 0..127
  const int dh  = (tid & 1) * 64;

  const int BND[5] = {0, 8, 17, 25, 34};
  const int pp    = (qt < 8) ? qt : (15 - qt);
  const int phase = (qt < 8) ? 0 : 1;
  const int LA    = 2 * pp + 2;

  float mv[4], lv[4];
  float M = -1e30f;
  #pragma unroll
  for (int jj = 0; jj < 4; ++jj) {
    bool inc = (phase == 0) ? (BND[jj] < LA) : (BND[jj + 1] > LA);
    int slot = (((h * 8 + pp) * 4 + jj) * 2) + phase;
    mv[jj] = inc ? PM[(size_t)slot * QB + r] : -1e30f;
    lv[jj] = inc ? PL[(size_t)slot * QB + r] : 0.f;
    M = fmaxf(M, mv[jj]);
  }
  float L = 0.f;
  float o[64];
  #pragma unroll
  for (int k2 = 0; k2 < 64; ++k2) o[k2] = 0.f;
  #pragma unroll
  for (int jj = 0; jj < 4; ++jj) {
    bool inc = (phase == 0) ? (BND[jj] < LA) : (BND[jj + 1] > LA);
    if (!inc) continue;
    int slot = (((h * 8 + pp) * 4 + jj) * 2) + phase;
    float w = exp2f(mv[jj] - M);
    L += lv[jj] * w;
    const ushort* src = PO + (size_t)slot * (QB * DD) + r * DD + dh;
    #pragma unroll
    for (int k4 = 0; k4 < 16; ++k4) {
      ushort4 u = *(const ushort4*)&src[4 * k4];
      o[4*k4+0] += bf2f(u.x) * w;
      o[4*k4+1] += bf2f(u.y) * w;
      o[4*k4+2] += bf2f(u.z) * w;
      o[4*k4+3] += bf2f(u.w) * w;
    }
  }
  float inv = 1.0f / L;
  float* op = O + ((size_t)(qt * QB + r) * HH + h) * DD + dh;
  #pragma unroll
  for (int k4 = 0; k4 < 16; ++k4) {
    float4 x = make_float4(o[4*k4]*inv, o[4*k4+1]*inv, o[4*k4+2]*inv, o[4*k4+3]*inv);
    *(float4*)&op[4 * k4] = x;
  }
}

extern "C" void kernel_launch(void* const* d_in, const int* in_sizes, int n_in,
                              void* d_out, int out_size, void* d_ws, size_t ws_size,
                              hipStream_t stream) {
  const float* Q = (const float*)d_in[0];
  const float* K = (const float*)d_in[1];
  const float* V = (const float*)d_in[2];
  float* O = (float*)d_out;

  const size_t po_elems = (size_t)1024 * QB * DD;        // bf16: 32 MB
  ushort* PO = (ushort*)d_ws;
  float*  PM = (float*)(PO + po_elems);                  // 1024*128 f32
  float*  PL = PM + (size_t)1024 * QB;

  attn_fwd<<<dim3(512), 256, 0, stream>>>(Q, K, V, PO, PM, PL);
  attn_merge<<<dim3(256), 256, 0, stream>>>(PO, PM, PL, O);
}